// Round 19
// baseline (339.644 us; speedup 1.0000x reference)
//
#include <hip/hip_runtime.h>
#include <math.h>

#define S_LEN 512
#define CH 8
#define NSEG 97            // segments; 98 nodes over [-15, 9.5]
#define TBL_L0 -15.0f
#define TBL_INVH 4.0f
#define TBL_H 0.25f

__device__ __forceinline__ float fast_rcp(float x) { return __builtin_amdgcn_rcpf(x); }
__device__ __forceinline__ float fast_rsq(float x) { return __builtin_amdgcn_rsqf(x); }
__device__ __forceinline__ float exp2s(float x)    { return __builtin_amdgcn_exp2f(x); }

// quad_perm DPP add (pure VALU)
template <int CTRL>
__device__ __forceinline__ float dpp_add(float v) {
    int vi = __builtin_bit_cast(int, v);
    int t  = __builtin_amdgcn_update_dpp(vi, vi, CTRL, 0xF, 0xF, true);
    return v + __builtin_bit_cast(float, t);
}

// R19: R17's algorithm (rotated basis, dx-staged LDS, PWL s(l2z) table,
// G pressure fold, log2-kappa), but SCALAR with the 128 points of one batch
// element split across 2 waves (1 point/lane). 4096 blocks x 128 thr ->
// 8192 waves -> 8 waves/SIMD (2x R17's occupancy) to hide the per-step
// serial chain. LDS <= 10 KB so 16 blocks/CU fit (thread-capped).
__global__ __launch_bounds__(128, 6) void prnn_kernel(
    const float* __restrict__ x,
    const float* __restrict__ W1,
    const float* __restrict__ W2,
    float* __restrict__ out)
{
    const double MUd = 3130.0 / 2.6;
    const double Cd  = 0.003407;
    const double K2d = 1.4426950408889634 / Cd;          // log2(e)/C
    const double S3  = 1.7320508075688772;
    const float MU      = (float)MUd;
    const float MUS3    = (float)(MUd * S3);
    const float CP      = (float)(7825.0 / 3.0);
    const float AH      = 64.8f;
    const float TMC     = (float)(3.0 * MUd * Cd);       // 3*mu*C
    const float MQ      = (float)(-K2d / (3.0 * MUd));   // -K2/(3mu)
    const float KA0     = (float)(1.4492898 + (64.8 / (3.0 * MUd)) * K2d); // 9.047
    const float I3      = (float)(1.0 / 3.0);
    const float IS3     = (float)(1.0 / S3);
    const float LOG2E   = 1.4426950408889634f;
    const float LN08    = (float)(0.8 * 0.6931471805599453);

    const int tid  = threadIdx.x;      // material point index m in [0,128)
    const int lane = tid & 63;
    const int wv   = tid >> 6;
    const int b    = blockIdx.x;

    __shared__ float2 xs01[S_LEN];           // dx0,dx1 (4 KB, shared by block)
    __shared__ float  xs2g[S_LEN];           // dx2 (2 KB)
    __shared__ float  part[2][CH][3][16];    // 3 KB (also G scratch at startup)
    __shared__ float2 wtab[NSEG];            // 776 B

    // ---- build s(l2z) = A - 3muC*W(2^l2z) PWL table (startup only) ----
    {
        float wn = 0.0f;
        if (tid <= NSEG) {                   // 98 nodes
            const float sarg = TBL_L0 + (float)tid * TBL_H;
            const float z = exp2s(sarg);
            float w = fmaxf(LN08 * sarg, z * (1.0f - z));
            #pragma unroll
            for (int it = 0; it < 4; ++it) {
                const float y   = exp2s(w * LOG2E);
                const float g   = w * y;
                const float F   = g - z;
                const float Fp  = g + y;
                const float den = Fp*Fp - 0.5f*((F*y)*(2.0f + w));
                w = w - (F*Fp)*fast_rcp(den);
            }
            wn = w;
            ((float*)wtab)[tid] = wn;        // park nodes (194 float slots >= 98)
        }
        __syncthreads();
        float wnext = 0.0f;
        if (tid < NSEG) wnext = ((float*)wtab)[tid + 1];
        __syncthreads();
        if (tid < NSEG) {
            const float sl = -TMC * (wnext - wn) * TBL_INVH;
            const float bi = (AH - TMC * wn) - sl * (TBL_L0 + (float)tid * TBL_H);
            wtab[tid] = (float2){sl, bi};
        }
        // no barrier needed yet: next use of wtab is after more __syncthreads
    }

    // Rotated per-point maps for point m = tid
    float P[3], Mr[3], T3[3], pvr[3];
    #pragma unroll
    for (int f = 0; f < 3; ++f) {
        const float av = W1[(tid*3 + 0)*3 + f];
        const float bv = W1[(tid*3 + 1)*3 + f];
        const float cv = W1[(tid*3 + 2)*3 + f];
        P[f]   = MU*(av + bv);
        Mr[f]  = MUS3*(av - bv);
        T3[f]  = MUS3*cv;
        pvr[f] = CP*(av + bv);
    }
    float wp[3], wm[3], w3[3], ws[3];
    #pragma unroll
    for (int o = 0; o < 3; ++o) {
        const float w0  = W2[o*384 + tid*3 + 0];
        const float w1  = W2[o*384 + tid*3 + 1];
        const float wsh = W2[o*384 + tid*3 + 2];
        wp[o] = I3 *(w0 + w1);
        wm[o] = IS3*(w0 - w1);
        w3[o] = IS3*wsh;
        ws[o] = w0 + w1;
    }

    // G fold: per-wave butterfly, cross-wave sum via part scratch
    float gsel0 = 0.f, gsel1 = 0.f, gsel2 = 0.f;
    {
        #pragma unroll
        for (int o = 0; o < 3; ++o)
            #pragma unroll
            for (int f = 0; f < 3; ++f) {
                float g = ws[o] * pvr[f];
                #pragma unroll
                for (int mm = 1; mm < 64; mm <<= 1) g += __shfl_xor(g, mm, 64);
                if (lane == 0) part[wv][0][o][f] = g;
            }
        __syncthreads();
        if (tid < 24) {
            const int ro = tid % 3;
            gsel0 = part[0][0][ro][0] + part[1][0][ro][0];
            gsel1 = part[0][0][ro][1] + part[1][0][ro][1];
            gsel2 = part[0][0][ro][2] + part[1][0][ro][2];
        }
        __syncthreads();
    }

    // dx staging (both waves cooperate; barrier before use)
    const float* xb = x + (size_t)b * (S_LEN*3);
    for (int i = tid; i < S_LEN; i += 128) {
        const float c0 = xb[i*3 + 0], c1 = xb[i*3 + 1], c2 = xb[i*3 + 2];
        float p0 = 0.f, p1 = 0.f, p2 = 0.f;
        if (i > 0) { p0 = xb[i*3 - 3]; p1 = xb[i*3 - 2]; p2 = xb[i*3 - 1]; }
        xs01[i] = (float2){ c0 - p0, c1 - p1 };
        xs2g[i] = c2 - p2;
    }
    __syncthreads();

    float sp = 0.f, sm = 0.f, s3 = 0.f, ka2 = KA0;
    float* outb = out + (size_t)b * (S_LEN*3);
    const int rtt0 = (tid < 24) ? (tid / 3) : 0;

    #pragma unroll 1
    for (int tc = 0; tc < S_LEN; tc += CH) {
        // finish-block absolute x prefetch (wave-0 lanes < 24 only)
        float fx0 = 0.f, fx1 = 0.f, fx2 = 0.f;
        if (tid < 24) {
            const float* xrow = xb + (size_t)(tc + rtt0)*3;
            fx0 = xrow[0]; fx1 = xrow[1]; fx2 = xrow[2];
        }

        #pragma unroll
        for (int tt = 0; tt < CH; ++tt) {
            const int t = tc + tt;
            const float2 dx01 = xs01[t];
            const float  dx2  = xs2g[t];
            const float dx0 = dx01.x, dx1 = dx01.y;

            // rotated trial: (p, m, d3) = R*dx + state
            const float p  = __builtin_fmaf(P[0], dx0,
                              __builtin_fmaf(P[1], dx1,
                              __builtin_fmaf(P[2], dx2, sp)));
            const float m  = __builtin_fmaf(Mr[0], dx0,
                              __builtin_fmaf(Mr[1], dx1,
                              __builtin_fmaf(Mr[2], dx2, sm)));
            const float d3 = __builtin_fmaf(T3[0], dx0,
                              __builtin_fmaf(T3[1], dx1,
                              __builtin_fmaf(T3[2], dx2, s3)));

            // q^2 = p^2 + m^2 + d3^2 + eps
            const float h  = __builtin_fmaf(p, p,
                              __builtin_fmaf(m, m,
                              __builtin_fmaf(d3, d3, 1e-24f)));
            const float qi = fast_rsq(h);
            const float q  = h * qi;

            // s = A - 3muC*W(2^l2z); l2z = q*MQ + ka2
            const float g   = q * MQ;
            const float l2z = g + ka2;
            const float fi  = __builtin_fmaf(l2z, TBL_INVH, -TBL_L0*TBL_INVH);
            const unsigned ii = (unsigned)fi;    // saturating: <0 -> 0; max 96 by KA0 bound
            const float2 tb = wtab[ii];
            const float sv  = __builtin_fmaf(tb.x, l2z, tb.y);
            const float u   = fminf(sv*qi, 1.0f);
            ka2 = __builtin_fmaf(-u, g, l2z);    // exact: ka2 + MQ*max(q-s,0)

            // radial return in rotated basis
            sp = u*p; sm = u*m; s3 = u*d3;

            // fc2 (rotated rows)
            float c0 = __builtin_fmaf(wp[0], sp, __builtin_fmaf(wm[0], sm, w3[0]*s3));
            float c1 = __builtin_fmaf(wp[1], sp, __builtin_fmaf(wm[1], sm, w3[1]*s3));
            float c2 = __builtin_fmaf(wp[2], sp, __builtin_fmaf(wm[2], sm, w3[2]*s3));

            // 2-stage DPP quad reduce -> 16 partials/wave
            c0 = dpp_add<0xB1>(c0); c0 = dpp_add<0x4E>(c0);
            c1 = dpp_add<0xB1>(c1); c1 = dpp_add<0x4E>(c1);
            c2 = dpp_add<0xB1>(c2); c2 = dpp_add<0x4E>(c2);
            if ((lane & 3) == 0) {
                const int g16 = lane >> 2;       // 0..15
                part[wv][tt][0][g16] = c0;
                part[wv][tt][1][g16] = c1;
                part[wv][tt][2][g16] = c2;
            }
        }
        __syncthreads();
        // finish: wave-0 lanes <24 -> (tt=r/3, o=r%3); sum both waves' 16 slots
        if (tid < 24) {
            const int rtt = tid / 3, ro = tid - rtt*3;
            const float4* p0 = (const float4*)&part[0][rtt][ro][0];
            const float4* p1 = (const float4*)&part[1][rtt][ro][0];
            float s = 0.0f;
            #pragma unroll
            for (int k = 0; k < 4; ++k) {
                const float4 va = p0[k], vb = p1[k];
                s += ((va.x + va.y) + (va.z + va.w))
                   + ((vb.x + vb.y) + (vb.z + vb.w));
            }
            s = __builtin_fmaf(gsel0, fx0, s);
            s = __builtin_fmaf(gsel1, fx1, s);
            s = __builtin_fmaf(gsel2, fx2, s);
            outb[tc*3 + tid] = s;
        }
        __syncthreads();
    }
}

extern "C" void kernel_launch(void* const* d_in, const int* in_sizes, int n_in,
                              void* d_out, int out_size, void* d_ws, size_t ws_size,
                              hipStream_t stream) {
    const float* x  = (const float*)d_in[0];
    const float* W1 = (const float*)d_in[1];
    const float* W2 = (const float*)d_in[2];
    float* out = (float*)d_out;
    prnn_kernel<<<4096, 128, 0, stream>>>(x, W1, W2, out);
}

// Round 20
// 284.420 us; speedup vs baseline: 1.1942x; 1.1942x over previous
//
#include <hip/hip_runtime.h>
#include <math.h>

#define S_LEN 512
#define CH 8
#define NSEG 128
#define TBL_L0 -22.0f
#define TBL_INVH 4.0f
#define TBL_H 0.25f

typedef float v2f __attribute__((ext_vector_type(2)));

__device__ __forceinline__ float fast_rcp(float x) { return __builtin_amdgcn_rcpf(x); }
__device__ __forceinline__ float fast_rsq(float x) { return __builtin_amdgcn_rsqf(x); }
__device__ __forceinline__ float exp2s(float x)    { return __builtin_amdgcn_exp2f(x); }
__device__ __forceinline__ v2f rsqv(v2f a)  { return (v2f){fast_rsq(a.x), fast_rsq(a.y)}; }
__device__ __forceinline__ v2f minv(v2f a, v2f b) { return __builtin_elementwise_min(a, b); }
__device__ __forceinline__ v2f vfma(v2f a, v2f b, v2f c) {
    return (v2f){ __builtin_fmaf(a.x, b.x, c.x), __builtin_fmaf(a.y, b.y, c.y) };
}

// quad_perm DPP add (pure VALU)
template <int CTRL>
__device__ __forceinline__ float dpp_add(float v) {
    int vi = __builtin_bit_cast(int, v);
    int t  = __builtin_amdgcn_update_dpp(vi, vi, CTRL, 0xF, 0xF, true);
    return v + __builtin_bit_cast(float, t);
}

// wave-uniform broadcast of lane l's value (l compile-time)
__device__ __forceinline__ float rlane(float v, int l) {
    return __builtin_bit_cast(float, __builtin_amdgcn_readlane(__builtin_bit_cast(int, v), l));
}

// R17 algorithm (rotated basis, PWL s(l2z) table, G pressure fold, log2-kappa,
// DPP reduce, barrier-free per-wave loop). R20: dx is REGISTER-staged — lane
// l (<24) of one VGPR holds dx element l of the current 8-step chunk
// (double-buffered, per-chunk masked global prefetch); per step 3 v_readlane
// broadcasts replace the 2 LDS dx reads (cuts ~120cyc off the serial chain).
__global__ __launch_bounds__(128, 4) void prnn_kernel(
    const float* __restrict__ x,
    const float* __restrict__ W1,
    const float* __restrict__ W2,
    float* __restrict__ out)
{
    const double MUd = 3130.0 / 2.6;
    const double Cd  = 0.003407;
    const double K2d = 1.4426950408889634 / Cd;          // log2(e)/C
    const double S3  = 1.7320508075688772;
    const float MU      = (float)MUd;
    const float MUS3    = (float)(MUd * S3);
    const float CP      = (float)(7825.0 / 3.0);
    const float AH      = 64.8f;
    const float TMC     = (float)(3.0 * MUd * Cd);       // 3*mu*C
    const float MQ      = (float)(-K2d / (3.0 * MUd));   // -K2/(3mu)
    const float KA0     = (float)(1.4492898 + (64.8 / (3.0 * MUd)) * K2d);
    const float I3      = (float)(1.0 / 3.0);
    const float IS3     = (float)(1.0 / S3);
    const float LOG2E   = 1.4426950408889634f;
    const float LN08    = (float)(0.8 * 0.6931471805599453);

    const int tid  = threadIdx.x;
    const int lane = tid & 63;
    const int wv   = tid >> 6;
    const int b    = blockIdx.x * 2 + wv;

    __shared__ float  part[2][CH][3][17];    // 3.3 KB
    __shared__ float2 wtab[NSEG];            // 1 KB

    // ---- build s(l2z) = A - 3muC*W(2^l2z) PWL table (startup only) ----
    {
        float wn = 0.0f;
        if (tid <= NSEG) {
            const float sarg = TBL_L0 + (float)tid * TBL_H;
            const float z = exp2s(sarg);
            float w = fmaxf(LN08 * sarg, z * (1.0f - z));
            #pragma unroll
            for (int it = 0; it < 4; ++it) {
                const float y   = exp2s(w * LOG2E);
                const float g   = w * y;
                const float F   = g - z;
                const float Fp  = g + y;
                const float den = Fp*Fp - 0.5f*((F*y)*(2.0f + w));
                w = w - (F*Fp)*fast_rcp(den);
            }
            wn = w;
            ((float*)wtab)[tid] = wn;
        }
        __syncthreads();
        float wnext = 0.0f;
        if (tid < NSEG) wnext = ((float*)wtab)[tid + 1];
        __syncthreads();
        if (tid < NSEG) {
            const float sl = -TMC * (wnext - wn) * TBL_INVH;
            const float bi = (AH - TMC * wn) - sl * (TBL_L0 + (float)tid * TBL_H);
            wtab[tid] = (float2){sl, bi};
        }
        __syncthreads();
    }

    // Rotated per-point maps
    v2f P[3], Mr[3], T3[3], pv[3];
    #pragma unroll
    for (int f = 0; f < 3; ++f) {
        const int mA = lane, mB = lane + 64;
        v2f av = (v2f){ W1[(mA*3 + 0)*3 + f], W1[(mB*3 + 0)*3 + f] };
        v2f bv = (v2f){ W1[(mA*3 + 1)*3 + f], W1[(mB*3 + 1)*3 + f] };
        v2f cv = (v2f){ W1[(mA*3 + 2)*3 + f], W1[(mB*3 + 2)*3 + f] };
        P[f]  = MU*(av + bv);
        Mr[f] = MUS3*(av - bv);
        T3[f] = MUS3*cv;
        pv[f] = CP*(av + bv);
    }
    v2f wp[3], wm[3], w3[3];
    float gsel0, gsel1, gsel2;
    {
        float G[3][3];
        #pragma unroll
        for (int o = 0; o < 3; ++o) {
            v2f w0 = (v2f){ W2[o*384 + lane*3 + 0], W2[o*384 + (lane+64)*3 + 0] };
            v2f w1 = (v2f){ W2[o*384 + lane*3 + 1], W2[o*384 + (lane+64)*3 + 1] };
            v2f wsh= (v2f){ W2[o*384 + lane*3 + 2], W2[o*384 + (lane+64)*3 + 2] };
            wp[o] = I3 *(w0 + w1);
            wm[o] = IS3*(w0 - w1);
            w3[o] = IS3*wsh;
            v2f ws = w0 + w1;
            #pragma unroll
            for (int f = 0; f < 3; ++f) {
                v2f gv = ws * pv[f];
                float g = gv.x + gv.y;
                #pragma unroll
                for (int mm = 1; mm < 64; mm <<= 1) g += __shfl_xor(g, mm, 64);
                G[o][f] = g;
            }
        }
        const int ro = lane % 3;
        gsel0 = (ro == 0) ? G[0][0] : (ro == 1) ? G[1][0] : G[2][0];
        gsel1 = (ro == 0) ? G[0][1] : (ro == 1) ? G[1][1] : G[2][1];
        gsel2 = (ro == 0) ? G[0][2] : (ro == 1) ? G[1][2] : G[2][2];
    }

    const float* xb = x + (size_t)b * (S_LEN*3);

    // dx chunk 0 into register (lane l < 24 holds dx element l)
    float vx_cur = 0.0f;
    if (lane < 24) {
        const float xc  = xb[lane];
        const float xpv = (lane >= 3) ? xb[lane - 3] : 0.0f;
        vx_cur = xc - xpv;
    }

    v2f sp = (v2f){0.f,0.f}, sm = sp, s3 = sp;
    v2f ka2 = (v2f){KA0, KA0};
    float* outb = out + (size_t)b * (S_LEN*3);
    const int rtt0 = (lane < 24) ? (lane / 3) : 0;

    #pragma unroll 1
    for (int tc = 0; tc < S_LEN; tc += CH) {
        // prefetch next dx chunk (wrap on last iter; lanes 0..2 guarded)
        const int tn = (tc + CH < S_LEN) ? (tc + CH) : 0;
        float vx_nxt = 0.0f;
        if (lane < 24) {
            const int e = tn*3 + lane;
            const float xc  = xb[e];
            const float xpv = (e >= 3) ? xb[e - 3] : 0.0f;
            vx_nxt = xc - xpv;
        }
        // prefetch finish-block absolute x (3 scalars, hidden under the body)
        const float* xrow = xb + (size_t)(tc + rtt0)*3;
        const float fx0 = xrow[0], fx1 = xrow[1], fx2 = xrow[2];

        #pragma unroll
        for (int tt = 0; tt < CH; ++tt) {
            const float dx0 = rlane(vx_cur, tt*3 + 0);
            const float dx1 = rlane(vx_cur, tt*3 + 1);
            const float dx2 = rlane(vx_cur, tt*3 + 2);

            // rotated trial: (p, m, d3) = R*dx + state
            v2f p  = P[0]*dx0 + P[1]*dx1 + P[2]*dx2 + sp;
            v2f m  = Mr[0]*dx0 + Mr[1]*dx1 + Mr[2]*dx2 + sm;
            v2f d3 = T3[0]*dx0 + T3[1]*dx1 + T3[2]*dx2 + s3;

            // q^2 = p^2 + m^2 + d3^2 + eps
            v2f h = vfma(p, p, vfma(m, m, vfma(d3, d3, (v2f){1e-24f,1e-24f})));
            v2f qi = rsqv(h);
            v2f q  = h * qi;

            // s = A - 3muC*W(2^l2z); l2z = q*MQ + ka2
            v2f g   = q * MQ;
            v2f l2z = g + ka2;
            const float fix = __builtin_fmaf(l2z.x, TBL_INVH, -TBL_L0*TBL_INVH);
            const float fiy = __builtin_fmaf(l2z.y, TBL_INVH, -TBL_L0*TBL_INVH);
            const unsigned ix = (unsigned)fix;   // saturating cvt (<0, NaN -> 0)
            const unsigned iy = (unsigned)fiy;   // top bounded by l2z <= 9.05
            const float2 tx = wtab[ix];
            const float2 ty = wtab[iy];
            v2f sv = (v2f){ __builtin_fmaf(tx.x, l2z.x, tx.y),
                            __builtin_fmaf(ty.x, l2z.y, ty.y) };
            v2f u   = minv(sv*qi, (v2f){1.0f,1.0f});
            ka2 = vfma(-u, g, l2z);              // exact: ka2 + MQ*max(q-s,0)

            // radial return in rotated basis
            sp = u*p; sm = u*m; s3 = u*d3;

            // fc2 (rotated rows)
            v2f a0 = wp[0]*sp + wm[0]*sm + w3[0]*s3;
            v2f a1 = wp[1]*sp + wm[1]*sm + w3[1]*s3;
            v2f a2 = wp[2]*sp + wm[2]*sm + w3[2]*s3;
            float c0 = a0.x + a0.y;
            float c1 = a1.x + a1.y;
            float c2 = a2.x + a2.y;

            // 4-lane reduce via DPP quad_perm
            c0 = dpp_add<0xB1>(c0); c0 = dpp_add<0x4E>(c0);
            c1 = dpp_add<0xB1>(c1); c1 = dpp_add<0x4E>(c1);
            c2 = dpp_add<0xB1>(c2); c2 = dpp_add<0x4E>(c2);
            if ((lane & 3) == 0) {
                const int g16 = lane >> 2;
                part[wv][tt][0][g16] = c0;
                part[wv][tt][1][g16] = c1;
                part[wv][tt][2][g16] = c2;
            }
        }
        // finish (same wave, DS program order): lane r<24 -> (tt=r/3, o=r%3)
        if (lane < 24) {
            const int rtt = lane / 3, ro = lane - rtt*3;
            const float4* pp = (const float4*)&part[wv][rtt][ro][0];
            const float4 v0 = pp[0], v1 = pp[1], v2v = pp[2], v3 = pp[3];
            float s = ((v0.x + v0.y) + (v0.z + v0.w))
                    + ((v1.x + v1.y) + (v1.z + v1.w))
                    + ((v2v.x + v2v.y) + (v2v.z + v2v.w))
                    + ((v3.x + v3.y) + (v3.z + v3.w));
            s = __builtin_fmaf(gsel0, fx0, s);
            s = __builtin_fmaf(gsel1, fx1, s);
            s = __builtin_fmaf(gsel2, fx2, s);
            outb[tc*3 + lane] = s;
        }
        vx_cur = vx_nxt;
    }
}

extern "C" void kernel_launch(void* const* d_in, const int* in_sizes, int n_in,
                              void* d_out, int out_size, void* d_ws, size_t ws_size,
                              hipStream_t stream) {
    const float* x  = (const float*)d_in[0];
    const float* W1 = (const float*)d_in[1];
    const float* W2 = (const float*)d_in[2];
    float* out = (float*)d_out;
    prnn_kernel<<<2048, 128, 0, stream>>>(x, W1, W2, out);
}

// Round 21
// 280.979 us; speedup vs baseline: 1.2088x; 1.0122x over previous
//
#include <hip/hip_runtime.h>
#include <math.h>

#define S_LEN 512
#define CH 8
#define NSEG 128
#define TBL_L0 -22.0f
#define TBL_INVH 4.0f
#define TBL_H 0.25f

__device__ __forceinline__ float fast_rcp(float x) { return __builtin_amdgcn_rcpf(x); }
__device__ __forceinline__ float fast_rsq(float x) { return __builtin_amdgcn_rsqf(x); }
__device__ __forceinline__ float exp2s(float x)    { return __builtin_amdgcn_exp2f(x); }

// quad_perm DPP add (pure VALU)
template <int CTRL>
__device__ __forceinline__ float dpp_add(float v) {
    int vi = __builtin_bit_cast(int, v);
    int t  = __builtin_amdgcn_update_dpp(vi, vi, CTRL, 0xF, 0xF, true);
    return v + __builtin_bit_cast(float, t);
}

// R17 algorithm (rotated basis, dx staged in LDS, PWL s(l2z) table, G fold,
// log2-kappa, DPP reduce, barrier-free per-wave loop) with the v2f point-pair
// HAND-SCALARIZED into two independent chains A (point=lane) / B (lane+64).
// Rationale: v_pk ops lock the two chains; scalar chains let the scheduler
// fill chain A's ~120cyc table-gather stall with chain B's work (R14 showed
// +11pts VALUBusy from scalarization; this version drops R14's baggage).
__global__ __launch_bounds__(128, 4) void prnn_kernel(
    const float* __restrict__ x,
    const float* __restrict__ W1,
    const float* __restrict__ W2,
    float* __restrict__ out)
{
    const double MUd = 3130.0 / 2.6;
    const double Cd  = 0.003407;
    const double K2d = 1.4426950408889634 / Cd;          // log2(e)/C
    const double S3  = 1.7320508075688772;
    const float MU      = (float)MUd;
    const float MUS3    = (float)(MUd * S3);
    const float CP      = (float)(7825.0 / 3.0);
    const float AH      = 64.8f;
    const float TMC     = (float)(3.0 * MUd * Cd);       // 3*mu*C
    const float MQ      = (float)(-K2d / (3.0 * MUd));   // -K2/(3mu)
    const float KA0     = (float)(1.4492898 + (64.8 / (3.0 * MUd)) * K2d);
    const float I3      = (float)(1.0 / 3.0);
    const float IS3     = (float)(1.0 / S3);
    const float LOG2E   = 1.4426950408889634f;
    const float LN08    = (float)(0.8 * 0.6931471805599453);

    const int tid  = threadIdx.x;
    const int lane = tid & 63;
    const int wv   = tid >> 6;
    const int b    = blockIdx.x * 2 + wv;

    __shared__ float2 xs01[2][S_LEN];        // dx0,dx1 (8 KB)
    __shared__ float  xs2g[2][S_LEN];        // dx2 (4 KB)
    __shared__ float  part[2][CH][3][17];    // 3.3 KB
    __shared__ float2 wtab[NSEG];            // 1 KB

    // ---- build s(l2z) = A - 3muC*W(2^l2z) PWL table (startup only) ----
    {
        float wn = 0.0f;
        if (tid <= NSEG) {
            const float sarg = TBL_L0 + (float)tid * TBL_H;
            const float z = exp2s(sarg);
            float w = fmaxf(LN08 * sarg, z * (1.0f - z));
            #pragma unroll
            for (int it = 0; it < 4; ++it) {
                const float y   = exp2s(w * LOG2E);
                const float g   = w * y;
                const float F   = g - z;
                const float Fp  = g + y;
                const float den = Fp*Fp - 0.5f*((F*y)*(2.0f + w));
                w = w - (F*Fp)*fast_rcp(den);
            }
            wn = w;
            ((float*)wtab)[tid] = wn;
        }
        __syncthreads();
        float wnext = 0.0f;
        if (tid < NSEG) wnext = ((float*)wtab)[tid + 1];
        __syncthreads();
        if (tid < NSEG) {
            const float sl = -TMC * (wnext - wn) * TBL_INVH;
            const float bi = (AH - TMC * wn) - sl * (TBL_L0 + (float)tid * TBL_H);
            wtab[tid] = (float2){sl, bi};
        }
        __syncthreads();
    }

    // Rotated per-point maps, separate for chains A and B
    float PA[3], PB[3], MrA[3], MrB[3], TA[3], TB[3], pvA[3], pvB[3];
    #pragma unroll
    for (int f = 0; f < 3; ++f) {
        const int mA = lane, mB = lane + 64;
        const float avA = W1[(mA*3 + 0)*3 + f], avB = W1[(mB*3 + 0)*3 + f];
        const float bvA = W1[(mA*3 + 1)*3 + f], bvB = W1[(mB*3 + 1)*3 + f];
        const float cvA = W1[(mA*3 + 2)*3 + f], cvB = W1[(mB*3 + 2)*3 + f];
        PA[f]  = MU*(avA + bvA);    PB[f]  = MU*(avB + bvB);
        MrA[f] = MUS3*(avA - bvA);  MrB[f] = MUS3*(avB - bvB);
        TA[f]  = MUS3*cvA;          TB[f]  = MUS3*cvB;
        pvA[f] = CP*(avA + bvA);    pvB[f] = CP*(avB + bvB);
    }
    float wpA[3], wpB[3], wmA[3], wmB[3], w3A[3], w3B[3];
    float gsel0, gsel1, gsel2;
    {
        float G[3][3];
        #pragma unroll
        for (int o = 0; o < 3; ++o) {
            const float w0A = W2[o*384 + lane*3 + 0], w0B = W2[o*384 + (lane+64)*3 + 0];
            const float w1A = W2[o*384 + lane*3 + 1], w1B = W2[o*384 + (lane+64)*3 + 1];
            const float wsA = W2[o*384 + lane*3 + 2], wsB = W2[o*384 + (lane+64)*3 + 2];
            wpA[o] = I3 *(w0A + w1A);   wpB[o] = I3 *(w0B + w1B);
            wmA[o] = IS3*(w0A - w1A);   wmB[o] = IS3*(w0B - w1B);
            w3A[o] = IS3*wsA;           w3B[o] = IS3*wsB;
            const float sA = w0A + w1A, sB = w0B + w1B;
            #pragma unroll
            for (int f = 0; f < 3; ++f) {
                float g = __builtin_fmaf(sA, pvA[f], sB * pvB[f]);
                #pragma unroll
                for (int mm = 1; mm < 64; mm <<= 1) g += __shfl_xor(g, mm, 64);
                G[o][f] = g;
            }
        }
        const int ro = lane % 3;
        gsel0 = (ro == 0) ? G[0][0] : (ro == 1) ? G[1][0] : G[2][0];
        gsel1 = (ro == 0) ? G[0][1] : (ro == 1) ? G[1][1] : G[2][1];
        gsel2 = (ro == 0) ? G[0][2] : (ro == 1) ? G[1][2] : G[2][2];
    }

    // Per-wave dx staging (same wave writes then reads -> DS program order)
    const float* xb = x + (size_t)b * (S_LEN*3);
    for (int i = lane; i < S_LEN; i += 64) {
        const float c0 = xb[i*3 + 0], c1 = xb[i*3 + 1], c2 = xb[i*3 + 2];
        float p0 = 0.f, p1 = 0.f, p2 = 0.f;
        if (i > 0) { p0 = xb[i*3 - 3]; p1 = xb[i*3 - 2]; p2 = xb[i*3 - 1]; }
        xs01[wv][i] = (float2){ c0 - p0, c1 - p1 };
        xs2g[wv][i] = c2 - p2;
    }

    float spA = 0.f, smA = 0.f, s3A = 0.f, ka2A = KA0;
    float spB = 0.f, smB = 0.f, s3B = 0.f, ka2B = KA0;
    float* outb = out + (size_t)b * (S_LEN*3);
    const int rtt0 = (lane < 24) ? (lane / 3) : 0;

    #pragma unroll 1
    for (int tc = 0; tc < S_LEN; tc += CH) {
        // prefetch finish-block absolute x (3 scalars, hidden under the body)
        const float* xrow = xb + (size_t)(tc + rtt0)*3;
        const float fx0 = xrow[0], fx1 = xrow[1], fx2 = xrow[2];

        #pragma unroll
        for (int tt = 0; tt < CH; ++tt) {
            const int t = tc + tt;
            const float2 dx01 = xs01[wv][t];
            const float  dx2  = xs2g[wv][t];
            const float dx0 = dx01.x, dx1 = dx01.y;

            // rotated trial, two independent chains
            const float pA = __builtin_fmaf(PA[0], dx0, __builtin_fmaf(PA[1], dx1, __builtin_fmaf(PA[2], dx2, spA)));
            const float pB = __builtin_fmaf(PB[0], dx0, __builtin_fmaf(PB[1], dx1, __builtin_fmaf(PB[2], dx2, spB)));
            const float mA = __builtin_fmaf(MrA[0], dx0, __builtin_fmaf(MrA[1], dx1, __builtin_fmaf(MrA[2], dx2, smA)));
            const float mB = __builtin_fmaf(MrB[0], dx0, __builtin_fmaf(MrB[1], dx1, __builtin_fmaf(MrB[2], dx2, smB)));
            const float dA = __builtin_fmaf(TA[0], dx0, __builtin_fmaf(TA[1], dx1, __builtin_fmaf(TA[2], dx2, s3A)));
            const float dB = __builtin_fmaf(TB[0], dx0, __builtin_fmaf(TB[1], dx1, __builtin_fmaf(TB[2], dx2, s3B)));

            // q^2 chains
            const float hA = __builtin_fmaf(pA, pA, __builtin_fmaf(mA, mA, __builtin_fmaf(dA, dA, 1e-24f)));
            const float hB = __builtin_fmaf(pB, pB, __builtin_fmaf(mB, mB, __builtin_fmaf(dB, dB, 1e-24f)));
            const float qiA = fast_rsq(hA);
            const float qiB = fast_rsq(hB);
            const float qA = hA * qiA;
            const float qB = hB * qiB;

            // table lookups, independent
            const float gA = qA * MQ;
            const float gB = qB * MQ;
            const float l2zA = gA + ka2A;
            const float l2zB = gB + ka2B;
            const float fiA = __builtin_fmaf(l2zA, TBL_INVH, -TBL_L0*TBL_INVH);
            const float fiB = __builtin_fmaf(l2zB, TBL_INVH, -TBL_L0*TBL_INVH);
            const unsigned iA = (unsigned)fiA;   // saturating cvt (<0, NaN -> 0)
            const unsigned iB = (unsigned)fiB;   // top bounded by l2z <= 9.05
            const float2 tbA = wtab[iA];
            const float2 tbB = wtab[iB];
            const float svA = __builtin_fmaf(tbA.x, l2zA, tbA.y);
            const float svB = __builtin_fmaf(tbB.x, l2zB, tbB.y);
            const float uA = fminf(svA*qiA, 1.0f);
            const float uB = fminf(svB*qiB, 1.0f);
            ka2A = __builtin_fmaf(-uA, gA, l2zA);
            ka2B = __builtin_fmaf(-uB, gB, l2zB);

            // radial return
            spA = uA*pA; smA = uA*mA; s3A = uA*dA;
            spB = uB*pB; smB = uB*mB; s3B = uB*dB;

            // fc2, per chain then pair add
            const float a0A = __builtin_fmaf(wpA[0], spA, __builtin_fmaf(wmA[0], smA, w3A[0]*s3A));
            const float a0B = __builtin_fmaf(wpB[0], spB, __builtin_fmaf(wmB[0], smB, w3B[0]*s3B));
            const float a1A = __builtin_fmaf(wpA[1], spA, __builtin_fmaf(wmA[1], smA, w3A[1]*s3A));
            const float a1B = __builtin_fmaf(wpB[1], spB, __builtin_fmaf(wmB[1], smB, w3B[1]*s3B));
            const float a2A = __builtin_fmaf(wpA[2], spA, __builtin_fmaf(wmA[2], smA, w3A[2]*s3A));
            const float a2B = __builtin_fmaf(wpB[2], spB, __builtin_fmaf(wmB[2], smB, w3B[2]*s3B));
            float c0 = a0A + a0B;
            float c1 = a1A + a1B;
            float c2 = a2A + a2B;

            // 4-lane reduce via DPP quad_perm
            c0 = dpp_add<0xB1>(c0); c0 = dpp_add<0x4E>(c0);
            c1 = dpp_add<0xB1>(c1); c1 = dpp_add<0x4E>(c1);
            c2 = dpp_add<0xB1>(c2); c2 = dpp_add<0x4E>(c2);
            if ((lane & 3) == 0) {
                const int g16 = lane >> 2;
                part[wv][tt][0][g16] = c0;
                part[wv][tt][1][g16] = c1;
                part[wv][tt][2][g16] = c2;
            }
        }
        // finish (same wave, DS program order): lane r<24 -> (tt=r/3, o=r%3)
        if (lane < 24) {
            const int rtt = lane / 3, ro = lane - rtt*3;
            const float4* pp = (const float4*)&part[wv][rtt][ro][0];
            const float4 v0 = pp[0], v1 = pp[1], v2v = pp[2], v3 = pp[3];
            float s = ((v0.x + v0.y) + (v0.z + v0.w))
                    + ((v1.x + v1.y) + (v1.z + v1.w))
                    + ((v2v.x + v2v.y) + (v2v.z + v2v.w))
                    + ((v3.x + v3.y) + (v3.z + v3.w));
            s = __builtin_fmaf(gsel0, fx0, s);
            s = __builtin_fmaf(gsel1, fx1, s);
            s = __builtin_fmaf(gsel2, fx2, s);
            outb[tc*3 + lane] = s;
        }
    }
}

extern "C" void kernel_launch(void* const* d_in, const int* in_sizes, int n_in,
                              void* d_out, int out_size, void* d_ws, size_t ws_size,
                              hipStream_t stream) {
    const float* x  = (const float*)d_in[0];
    const float* W1 = (const float*)d_in[1];
    const float* W2 = (const float*)d_in[2];
    float* out = (float*)d_out;
    prnn_kernel<<<2048, 128, 0, stream>>>(x, W1, W2, out);
}